// Round 1
// baseline (569.327 us; speedup 1.0000x reference)
//
#include <hip/hip_runtime.h>

#define D 64
#define TK 128        // codes staged per LDS tile (128*64*4 = 32 KB)
#define NCHUNK 8      // K split across blocks for occupancy
#define DECAYF 0.8f
#define OMDF 0.2f
#define EPSF 1e-5f

// ---------- kernel 0: e2[k] = sum_d emb[k][d]^2 ----------
__global__ void e2_kernel(const float* __restrict__ emb, float* __restrict__ e2, int K) {
    int k = blockIdx.x * blockDim.x + threadIdx.x;
    if (k >= K) return;
    const float4* p = reinterpret_cast<const float4*>(emb + (size_t)k * D);
    float s0 = 0.f, s1 = 0.f, s2 = 0.f, s3 = 0.f;
#pragma unroll
    for (int i = 0; i < 16; ++i) {
        float4 v = p[i];
        s0 += v.x * v.x; s1 += v.y * v.y; s2 += v.z * v.z; s3 += v.w * v.w;
    }
    e2[k] = (s0 + s1) + (s2 + s3);
}

// ---------- kernel 1: fused distance + argmin over a K-chunk ----------
// grid = (n/256) * NCHUNK blocks of 256 threads; one query per thread.
__global__ __launch_bounds__(256) void argmin_kernel(
    const float* __restrict__ x, const float* __restrict__ emb,
    const float* __restrict__ e2, float* __restrict__ pdist,
    int* __restrict__ pidx, int n, int K)
{
    __shared__ float se[TK * D];   // 32 KB
    __shared__ float se2[TK];

    const int chunk = blockIdx.x % NCHUNK;
    const int qb    = blockIdx.x / NCHUNK;
    const int q     = qb * 256 + threadIdx.x;

    // load this thread's query vector into registers (static indexing only)
    float xr[D];
    const float4* xp = reinterpret_cast<const float4*>(x + (size_t)q * D);
#pragma unroll
    for (int i = 0; i < 16; ++i) {
        float4 v = xp[i];
        xr[4*i+0] = v.x; xr[4*i+1] = v.y; xr[4*i+2] = v.z; xr[4*i+3] = v.w;
    }

    float best = 3.4e38f;
    int   bidx = 0;
    const int kc = K / NCHUNK;       // 1024
    const int k0 = chunk * kc;

    for (int t = 0; t < kc; t += TK) {
        __syncthreads();
        // cooperative stage: TK*D floats = 2048 float4 by 256 threads -> 8 each (coalesced)
        const float4* gsrc = reinterpret_cast<const float4*>(emb + (size_t)(k0 + t) * D);
        float4* ldst = reinterpret_cast<float4*>(se);
#pragma unroll
        for (int i = 0; i < 8; ++i)
            ldst[threadIdx.x + 256 * i] = gsrc[threadIdx.x + 256 * i];
        if (threadIdx.x < TK) se2[threadIdx.x] = e2[k0 + t + threadIdx.x];
        __syncthreads();

        for (int k = 0; k < TK; ++k) {
            const float4* ep = reinterpret_cast<const float4*>(se + k * D);
            float d0 = 0.f, d1 = 0.f, d2 = 0.f, d3 = 0.f;
#pragma unroll
            for (int i = 0; i < 16; ++i) {
                float4 v = ep[i];      // same address across lanes -> LDS broadcast
                d0 += xr[4*i+0] * v.x;
                d1 += xr[4*i+1] * v.y;
                d2 += xr[4*i+2] * v.z;
                d3 += xr[4*i+3] * v.w;
            }
            float dist = se2[k] - 2.0f * ((d0 + d1) + (d2 + d3));
            if (dist < best) { best = dist; bidx = k0 + t + k; }  // strict < keeps first (ref tie-break)
        }
    }
    pdist[(size_t)chunk * n + q] = best;
    pidx [(size_t)chunk * n + q] = bidx;
}

// ---------- kernel 2a: reduce chunks, emit index, count atomics ----------
__global__ void reduce_kernel(const float* __restrict__ pdist, const int* __restrict__ pidx,
                              float* __restrict__ out_ind, int* __restrict__ idxf,
                              float* __restrict__ counts, int n)
{
    int q = blockIdx.x * blockDim.x + threadIdx.x;
    if (q >= n) return;
    float best = pdist[q];
    int   bi   = pidx[q];
    for (int c = 1; c < NCHUNK; ++c) {                // ascending chunk order => first-min tie-break
        float dd = pdist[(size_t)c * n + q];
        int   ii = pidx [(size_t)c * n + q];
        if (dd < best) { best = dd; bi = ii; }
    }
    out_ind[q] = (float)bi;
    idxf[q]    = bi;
    atomicAdd(counts + bi, 1.0f);
}

// ---------- kernel 2b: gather quantize + scatter embed_sum (wave per query) ----------
__global__ void gather_scatter_kernel(const float* __restrict__ x, const float* __restrict__ emb,
                                      const int* __restrict__ idxf, float* __restrict__ quant,
                                      float* __restrict__ embed_sum, int n)
{
    int gid = blockIdx.x * blockDim.x + threadIdx.x;
    int q = gid >> 6;         // one 64-lane wave per query
    int d = gid & 63;
    if (q >= n) return;
    int k = idxf[q];
    quant[(size_t)q * D + d] = emb[(size_t)k * D + d];
    atomicAdd(embed_sum + (size_t)k * D + d, x[(size_t)q * D + d]);
}

// ---------- kernel 3a: EMA cluster_size (in place over counts) + total ----------
__global__ __launch_bounds__(256) void ema_cs_kernel(const float* __restrict__ cluster_size,
                                                     float* __restrict__ ncs, float* __restrict__ total_ws,
                                                     int K)
{
    __shared__ float red[256];
    float local = 0.f;
    for (int k = threadIdx.x; k < K; k += 256) {
        float v = cluster_size[k] * DECAYF + ncs[k] * OMDF;
        ncs[k] = v;
        local += v;
    }
    red[threadIdx.x] = local;
    __syncthreads();
    for (int s = 128; s > 0; s >>= 1) {
        if (threadIdx.x < s) red[threadIdx.x] += red[threadIdx.x + s];
        __syncthreads();
    }
    if (threadIdx.x == 0) total_ws[0] = red[0];
}

// ---------- kernel 3b: EMA embed_avg (in place over embed_sum) + normalize ----------
__global__ void ema_embed_kernel(const float* __restrict__ embed_avg,
                                 const float* __restrict__ ncs, const float* __restrict__ total_ws,
                                 float* __restrict__ nea, float* __restrict__ enorm, int K)
{
    int gid = blockIdx.x * blockDim.x + threadIdx.x;
    if (gid >= K * D) return;
    int k = gid >> 6;
    float total = total_ws[0];
    float v = embed_avg[gid] * DECAYF + nea[gid] * OMDF;
    nea[gid] = v;
    float c = ncs[k];
    float smoothed = (c + EPSF) / (total + (float)K * EPSF) * total;
    enorm[gid] = v / smoothed;
}

extern "C" void kernel_launch(void* const* d_in, const int* in_sizes, int n_in,
                              void* d_out, int out_size, void* d_ws, size_t ws_size,
                              hipStream_t stream) {
    const float* x            = (const float*)d_in[0];   // [n, 64]
    const float* emb          = (const float*)d_in[1];   // [K, 64]
    const float* cluster_size = (const float*)d_in[2];   // [K]
    const float* embed_avg    = (const float*)d_in[3];   // [K, 64]

    const int n = in_sizes[0] / D;   // 16384
    const int K = in_sizes[1] / D;   // 8192

    // output layout (all fp32): quantize | embed_ind | embed_normalized | new_cluster_size | new_embed_avg
    float* out     = (float*)d_out;
    float* quant   = out;                        // n*D
    float* out_ind = quant + (size_t)n * D;      // n
    float* enorm   = out_ind + n;                // K*D
    float* ncs     = enorm + (size_t)K * D;      // K    (accumulates counts, then EMA'd in place)
    float* nea     = ncs + K;                    // K*D  (accumulates embed_sum, then EMA'd in place)

    // workspace layout
    float* e2    = (float*)d_ws;                       // K
    float* pdist = e2 + K;                             // NCHUNK*n
    int*   pidx  = (int*)(pdist + (size_t)NCHUNK * n); // NCHUNK*n
    int*   idxf  = pidx + (size_t)NCHUNK * n;          // n
    float* total = (float*)(idxf + n);                 // 1

    // zero the accumulation targets (graph-capture-safe; deterministic per launch)
    hipMemsetAsync(ncs, 0, (size_t)K * sizeof(float), stream);
    hipMemsetAsync(nea, 0, (size_t)K * D * sizeof(float), stream);

    e2_kernel<<<(K + 255) / 256, 256, 0, stream>>>(emb, e2, K);
    argmin_kernel<<<(n / 256) * NCHUNK, 256, 0, stream>>>(x, emb, e2, pdist, pidx, n, K);
    reduce_kernel<<<(n + 255) / 256, 256, 0, stream>>>(pdist, pidx, out_ind, idxf, ncs, n);
    gather_scatter_kernel<<<((size_t)n * D + 255) / 256, 256, 0, stream>>>(x, emb, idxf, quant, nea, n);
    ema_cs_kernel<<<1, 256, 0, stream>>>(cluster_size, ncs, total, K);
    ema_embed_kernel<<<(K * D + 255) / 256, 256, 0, stream>>>(embed_avg, ncs, total, nea, enorm, K);
}

// Round 2
// 399.746 us; speedup vs baseline: 1.4242x; 1.4242x over previous
//
#include <hip/hip_runtime.h>

#define D 64
#define QB 64         // queries per block
#define KB 64         // codes per LDS tile
#define NCHUNK 4      // K split across blocks
#define SXS 68        // padded LDS row stride in dwords (breaks bank alignment)
#define DECAYF 0.8f
#define OMDF 0.2f
#define EPSF 1e-5f

// ---------- kernel 0: e2[k] = sum_d emb[k][d]^2 ----------
__global__ void e2_kernel(const float* __restrict__ emb, float* __restrict__ e2, int K) {
    int k = blockIdx.x * blockDim.x + threadIdx.x;
    if (k >= K) return;
    const float4* p = reinterpret_cast<const float4*>(emb + (size_t)k * D);
    float s0 = 0.f, s1 = 0.f, s2 = 0.f, s3 = 0.f;
#pragma unroll
    for (int i = 0; i < 16; ++i) {
        float4 v = p[i];
        s0 += v.x * v.x; s1 += v.y * v.y; s2 += v.z * v.z; s3 += v.w * v.w;
    }
    e2[k] = (s0 + s1) + (s2 + s3);
}

// ---------- kernel 1: register-tiled GEMM + fused argmin ----------
// 256 threads = 16 a-groups (queries) x 16 b-groups (codes); 4x4 micro-tile.
__global__ __launch_bounds__(256, 4) void argmin_kernel(
    const float* __restrict__ x, const float* __restrict__ emb,
    const float* __restrict__ e2, float* __restrict__ pdist,
    int* __restrict__ pidx, int n, int K)
{
    __shared__ float sx[QB * SXS];   // 17408 B
    __shared__ float se[KB * SXS];   // 17408 B
    __shared__ float se2[KB];        // 256 B

    const int tx    = threadIdx.x;
    const int b     = tx & 15;
    const int a     = tx >> 4;
    const int chunk = blockIdx.x % NCHUNK;
    const int qblk  = blockIdx.x / NCHUNK;
    const int q0    = qblk * QB;
    const int kc    = K / NCHUNK;      // 2048
    const int k0    = chunk * kc;
    const int NT    = kc / KB;         // 32

    // ---- stage x tile once (64 rows x 16 float4, 4 per thread) ----
    {
        const float4* xs = reinterpret_cast<const float4*>(x + (size_t)q0 * D);
#pragma unroll
        for (int i = 0; i < 4; ++i) {
            int flat = tx + 256 * i;               // [0,1024)
            int row = flat >> 4, col = flat & 15;
            *reinterpret_cast<float4*>(&sx[row * SXS + col * 4]) = xs[flat];
        }
    }

    float best[4] = {3.4e38f, 3.4e38f, 3.4e38f, 3.4e38f};
    int   bidx[4] = {0, 0, 0, 0};

    // ---- prefetch tile 0 into registers ----
    float4 pf[4];
    float  pe2 = 0.f;
    {
        const float4* es = reinterpret_cast<const float4*>(emb + (size_t)k0 * D);
#pragma unroll
        for (int i = 0; i < 4; ++i) pf[i] = es[tx + 256 * i];
        if (tx < KB) pe2 = e2[k0 + tx];
    }

    for (int t = 0; t < NT; ++t) {
        __syncthreads();   // previous tile's readers done (iter 0: covers x staging too)

        // write prefetched tile into LDS
#pragma unroll
        for (int i = 0; i < 4; ++i) {
            int flat = tx + 256 * i;
            int row = flat >> 4, col = flat & 15;
            *reinterpret_cast<float4*>(&se[row * SXS + col * 4]) = pf[i];
        }
        if (tx < KB) se2[tx] = pe2;

        // issue next tile's global loads early (latency hides under compute)
        if (t + 1 < NT) {
            const float4* es = reinterpret_cast<const float4*>(emb + (size_t)(k0 + (t + 1) * KB) * D);
#pragma unroll
            for (int i = 0; i < 4; ++i) pf[i] = es[tx + 256 * i];
            if (tx < KB) pe2 = e2[k0 + (t + 1) * KB + tx];
        }
        __syncthreads();

        float acc[4][4];
#pragma unroll
        for (int i = 0; i < 4; ++i)
#pragma unroll
            for (int j = 0; j < 4; ++j) acc[i][j] = 0.f;

#pragma unroll
        for (int d = 0; d < D; d += 4) {
            float4 xf[4], ef[4];
#pragma unroll
            for (int i = 0; i < 4; ++i)
                xf[i] = *reinterpret_cast<const float4*>(&sx[(a * 4 + i) * SXS + d]);
#pragma unroll
            for (int j = 0; j < 4; ++j)
                ef[j] = *reinterpret_cast<const float4*>(&se[(b + j * 16) * SXS + d]);
#pragma unroll
            for (int i = 0; i < 4; ++i)
#pragma unroll
                for (int j = 0; j < 4; ++j) {
                    acc[i][j] = fmaf(xf[i].x, ef[j].x, acc[i][j]);
                    acc[i][j] = fmaf(xf[i].y, ef[j].y, acc[i][j]);
                    acc[i][j] = fmaf(xf[i].z, ef[j].z, acc[i][j]);
                    acc[i][j] = fmaf(xf[i].w, ef[j].w, acc[i][j]);
                }
        }

        // fused argmin epilogue for this tile
        const int kbase = k0 + t * KB;
#pragma unroll
        for (int j = 0; j < 4; ++j) {
            float e2v  = se2[b + j * 16];
            int   kidx = kbase + b + j * 16;
#pragma unroll
            for (int i = 0; i < 4; ++i) {
                float dist = fmaf(-2.f, acc[i][j], e2v);
                if (dist < best[i]) { best[i] = dist; bidx[i] = kidx; }
            }
        }
    }

    // ---- reduce across the 16 b-lanes (same a-group) via shuffles ----
#pragma unroll
    for (int i = 0; i < 4; ++i) {
#pragma unroll
        for (int m = 1; m < 16; m <<= 1) {
            float od = __shfl_xor(best[i], m, 64);
            int   oi = __shfl_xor(bidx[i], m, 64);
            if (od < best[i] || (od == best[i] && oi < bidx[i])) { best[i] = od; bidx[i] = oi; }
        }
    }
    if (b == 0) {
#pragma unroll
        for (int i = 0; i < 4; ++i) {
            int q = q0 + a * 4 + i;
            pdist[(size_t)chunk * n + q] = best[i];
            pidx [(size_t)chunk * n + q] = bidx[i];
        }
    }
}

// ---------- kernel 2a: reduce chunks, emit index, count atomics ----------
__global__ void reduce_kernel(const float* __restrict__ pdist, const int* __restrict__ pidx,
                              float* __restrict__ out_ind, int* __restrict__ idxf,
                              float* __restrict__ counts, int n)
{
    int q = blockIdx.x * blockDim.x + threadIdx.x;
    if (q >= n) return;
    float best = pdist[q];
    int   bi   = pidx[q];
    for (int c = 1; c < NCHUNK; ++c) {              // ascending chunk order => first-min tie-break
        float dd = pdist[(size_t)c * n + q];
        int   ii = pidx [(size_t)c * n + q];
        if (dd < best || (dd == best && ii < bi)) { best = dd; bi = ii; }
    }
    out_ind[q] = (float)bi;
    idxf[q]    = bi;
    atomicAdd(counts + bi, 1.0f);
}

// ---------- kernel 2b: gather quantize + scatter embed_sum ----------
__global__ void gather_scatter_kernel(const float* __restrict__ x, const float* __restrict__ emb,
                                      const int* __restrict__ idxf, float* __restrict__ quant,
                                      float* __restrict__ embed_sum, int n)
{
    int gid = blockIdx.x * blockDim.x + threadIdx.x;
    int q = gid >> 6;
    int d = gid & 63;
    if (q >= n) return;
    int k = idxf[q];
    quant[(size_t)q * D + d] = emb[(size_t)k * D + d];
    atomicAdd(embed_sum + (size_t)k * D + d, x[(size_t)q * D + d]);
}

// ---------- kernel 3a: EMA cluster_size + total ----------
__global__ __launch_bounds__(256) void ema_cs_kernel(const float* __restrict__ cluster_size,
                                                     float* __restrict__ ncs, float* __restrict__ total_ws,
                                                     int K)
{
    __shared__ float red[256];
    float local = 0.f;
    for (int k = threadIdx.x; k < K; k += 256) {
        float v = cluster_size[k] * DECAYF + ncs[k] * OMDF;
        ncs[k] = v;
        local += v;
    }
    red[threadIdx.x] = local;
    __syncthreads();
    for (int s = 128; s > 0; s >>= 1) {
        if (threadIdx.x < s) red[threadIdx.x] += red[threadIdx.x + s];
        __syncthreads();
    }
    if (threadIdx.x == 0) total_ws[0] = red[0];
}

// ---------- kernel 3b: EMA embed_avg + normalize ----------
__global__ void ema_embed_kernel(const float* __restrict__ embed_avg,
                                 const float* __restrict__ ncs, const float* __restrict__ total_ws,
                                 float* __restrict__ nea, float* __restrict__ enorm, int K)
{
    int gid = blockIdx.x * blockDim.x + threadIdx.x;
    if (gid >= K * D) return;
    int k = gid >> 6;
    float total = total_ws[0];
    float v = embed_avg[gid] * DECAYF + nea[gid] * OMDF;
    nea[gid] = v;
    float c = ncs[k];
    float smoothed = (c + EPSF) / (total + (float)K * EPSF) * total;
    enorm[gid] = v / smoothed;
}

extern "C" void kernel_launch(void* const* d_in, const int* in_sizes, int n_in,
                              void* d_out, int out_size, void* d_ws, size_t ws_size,
                              hipStream_t stream) {
    const float* x            = (const float*)d_in[0];   // [n, 64]
    const float* emb          = (const float*)d_in[1];   // [K, 64]
    const float* cluster_size = (const float*)d_in[2];   // [K]
    const float* embed_avg    = (const float*)d_in[3];   // [K, 64]

    const int n = in_sizes[0] / D;   // 16384
    const int K = in_sizes[1] / D;   // 8192

    // output layout (fp32): quantize | embed_ind | embed_normalized | new_cluster_size | new_embed_avg
    float* out     = (float*)d_out;
    float* quant   = out;                        // n*D
    float* out_ind = quant + (size_t)n * D;      // n
    float* enorm   = out_ind + n;                // K*D
    float* ncs     = enorm + (size_t)K * D;      // K
    float* nea     = ncs + K;                    // K*D

    // workspace layout
    float* e2    = (float*)d_ws;                       // K
    float* pdist = e2 + K;                             // NCHUNK*n
    int*   pidx  = (int*)(pdist + (size_t)NCHUNK * n); // NCHUNK*n
    int*   idxf  = pidx + (size_t)NCHUNK * n;          // n
    float* total = (float*)(idxf + n);                 // 1

    hipMemsetAsync(ncs, 0, (size_t)K * sizeof(float), stream);
    hipMemsetAsync(nea, 0, (size_t)K * D * sizeof(float), stream);

    e2_kernel<<<(K + 255) / 256, 256, 0, stream>>>(emb, e2, K);
    argmin_kernel<<<(n / QB) * NCHUNK, 256, 0, stream>>>(x, emb, e2, pdist, pidx, n, K);
    reduce_kernel<<<(n + 255) / 256, 256, 0, stream>>>(pdist, pidx, out_ind, idxf, ncs, n);
    gather_scatter_kernel<<<((size_t)n * D + 255) / 256, 256, 0, stream>>>(x, emb, idxf, quant, nea, n);
    ema_cs_kernel<<<1, 256, 0, stream>>>(cluster_size, ncs, total, K);
    ema_embed_kernel<<<(K * D + 255) / 256, 256, 0, stream>>>(embed_avg, ncs, total, nea, enorm, K);
}

// Round 5
// 222.034 us; speedup vs baseline: 2.5641x; 1.8004x over previous
//
#include <hip/hip_runtime.h>

#define D 64
#define BM 128        // queries per block (held in registers)
#define BN 64         // codes per LDS tile
#define NCHUNK 8      // K split across blocks
#define NLIST (4 * NCHUNK)   // candidate lists: 2 per (chunk, wn-wave)
#define LDE 72        // padded LDS row stride in f16 elems (144 B)
#define DECAYF 0.8f
#define OMDF 0.2f
#define EPSF 1e-5f
#define INVS 4.8828125e-4f   // 2^-11

typedef _Float16 f16;
typedef _Float16 f16x8 __attribute__((ext_vector_type(8)));
typedef float f32x4 __attribute__((ext_vector_type(4)));

// ---------- convert emb fp32 -> f16 hi/lo pair (lo scaled by 2^11) ----------
__global__ void convertB_kernel(const float* __restrict__ emb, f16* __restrict__ eh,
                                f16* __restrict__ el, int total4) {
    int i = blockIdx.x * blockDim.x + threadIdx.x;
    if (i >= total4) return;
    float4 v = reinterpret_cast<const float4*>(emb)[i];
    union { f16 h[4]; uint2 u; } H, L;
    float f[4] = {v.x, v.y, v.z, v.w};
#pragma unroll
    for (int j = 0; j < 4; ++j) {
        f16 h = (f16)f[j];
        H.h[j] = h;
        L.h[j] = (f16)((f[j] - (float)h) * 2048.0f);
    }
    reinterpret_cast<uint2*>(eh)[i] = H.u;
    reinterpret_cast<uint2*>(el)[i] = L.u;
}

// ---------- e2[k] = sum_d emb[k][d]^2 (exact fp32) ----------
__global__ void e2_kernel(const float* __restrict__ emb, float* __restrict__ e2, int K) {
    int k = blockIdx.x * blockDim.x + threadIdx.x;
    if (k >= K) return;
    const float4* p = reinterpret_cast<const float4*>(emb + (size_t)k * D);
    float s0 = 0.f, s1 = 0.f, s2 = 0.f, s3 = 0.f;
#pragma unroll
    for (int i = 0; i < 16; ++i) {
        float4 v = p[i];
        s0 += v.x * v.x; s1 += v.y * v.y; s2 += v.z * v.z; s3 += v.w * v.w;
    }
    e2[k] = (s0 + s1) + (s2 + s3);
}

// ---------- MFMA 3-pass split-f16 distance + fused top-2 per (chunk, wn) ----------
// 4 waves = 2(wm query-split) x 2(wn code-split). Each (chunk,wn) writes its OWN
// two candidate lists -- no cross-wave write race (round-3/4 bug).
__global__ __launch_bounds__(256, 2) void argmin_kernel(
    const float* __restrict__ x, const f16* __restrict__ eh, const f16* __restrict__ el,
    const float* __restrict__ e2, int* __restrict__ pidx, int n, int K)
{
    __shared__ f16 sh[2][BN * LDE];
    __shared__ f16 sl[2][BN * LDE];
    __shared__ float se2[2][BN];

    const int tx   = threadIdx.x;
    const int lane = tx & 63;
    const int wid  = tx >> 6;
    const int wm   = wid >> 1, wn = wid & 1;
    const int lrow = lane & 15;
    const int lkg  = lane >> 4;

    const int chunk = blockIdx.x % NCHUNK;
    const int mblk  = blockIdx.x / NCHUNK;
    const int q0    = mblk * BM;
    const int kc    = K / NCHUNK;    // 1024
    const int k0    = chunk * kc;
    const int NT    = kc / BN;       // 16

    // ---- A fragments: fp32 x rows -> f16 hi/lo in registers ----
    f16x8 ah[4][2], al[4][2];
#pragma unroll
    for (int m = 0; m < 4; ++m)
#pragma unroll
        for (int ks = 0; ks < 2; ++ks) {
            int row = q0 + wm * 64 + m * 16 + lrow;
            const float4* p = reinterpret_cast<const float4*>(
                x + (size_t)row * D + ks * 32 + lkg * 8);
            float4 va = p[0], vb = p[1];
            float t[8] = {va.x, va.y, va.z, va.w, vb.x, vb.y, vb.z, vb.w};
#pragma unroll
            for (int j = 0; j < 8; ++j) {
                f16 h = (f16)t[j];
                ah[m][ks][j] = h;
                al[m][ks][j] = (f16)((t[j] - (float)h) * 2048.0f);
            }
        }

    // ---- top-2 state per C-slot: d1<=d2, tags packed (t1<<16)|t2 ----
    float d1[16], d2[16];
    unsigned int tp[16];
#pragma unroll
    for (int s = 0; s < 16; ++s) { d1[s] = 3.4e38f; d2[s] = 3.4e38f; tp[s] = 0; }

    // ---- prefetch tile 0 ----
    float4 ph[2], pl[2];
    float  pe2 = 0.f;
    {
        const float4* gh = reinterpret_cast<const float4*>(eh + (size_t)k0 * D);
        const float4* gl = reinterpret_cast<const float4*>(el + (size_t)k0 * D);
#pragma unroll
        for (int i = 0; i < 2; ++i) { ph[i] = gh[tx + 256 * i]; pl[i] = gl[tx + 256 * i]; }
        if (tx < BN) pe2 = e2[k0 + tx];
    }

#pragma unroll 1
    for (int tt = 0; tt < NT; ++tt) {
        const int cur = tt & 1;
#pragma unroll
        for (int i = 0; i < 2; ++i) {
            int c = tx + 256 * i;
            int row = c >> 3, c8 = c & 7;
            *reinterpret_cast<float4*>(&sh[cur][row * LDE + c8 * 8]) = ph[i];
            *reinterpret_cast<float4*>(&sl[cur][row * LDE + c8 * 8]) = pl[i];
        }
        if (tx < BN) se2[cur][tx] = pe2;
        if (tt + 1 < NT) {
            int kt = k0 + (tt + 1) * BN;
            const float4* gh = reinterpret_cast<const float4*>(eh + (size_t)kt * D);
            const float4* gl = reinterpret_cast<const float4*>(el + (size_t)kt * D);
#pragma unroll
            for (int i = 0; i < 2; ++i) { ph[i] = gh[tx + 256 * i]; pl[i] = gl[tx + 256 * i]; }
            if (tx < BN) pe2 = e2[kt + tx];
        }
        __syncthreads();

#pragma unroll
        for (int nf = 0; nf < 2; ++nf) {
            const int brow = wn * 32 + nf * 16 + lrow;
            f16x8 bh0 = *reinterpret_cast<const f16x8*>(&sh[cur][brow * LDE + 0 * 32 + lkg * 8]);
            f16x8 bh1 = *reinterpret_cast<const f16x8*>(&sh[cur][brow * LDE + 1 * 32 + lkg * 8]);
            f16x8 bl0 = *reinterpret_cast<const f16x8*>(&sl[cur][brow * LDE + 0 * 32 + lkg * 8]);
            f16x8 bl1 = *reinterpret_cast<const f16x8*>(&sl[cur][brow * LDE + 1 * 32 + lkg * 8]);
            const float e2v = se2[cur][brow];
            const int   tg  = tt * 64 + wn * 32 + nf * 16 + lrow;   // chunk-local code id

#pragma unroll
            for (int m = 0; m < 4; ++m) {
                f32x4 hh = {0.f, 0.f, 0.f, 0.f};
                f32x4 md = {0.f, 0.f, 0.f, 0.f};
                hh = __builtin_amdgcn_mfma_f32_16x16x32_f16(ah[m][0], bh0, hh, 0, 0, 0);
                hh = __builtin_amdgcn_mfma_f32_16x16x32_f16(ah[m][1], bh1, hh, 0, 0, 0);
                md = __builtin_amdgcn_mfma_f32_16x16x32_f16(al[m][0], bh0, md, 0, 0, 0);
                md = __builtin_amdgcn_mfma_f32_16x16x32_f16(al[m][1], bh1, md, 0, 0, 0);
                md = __builtin_amdgcn_mfma_f32_16x16x32_f16(ah[m][0], bl0, md, 0, 0, 0);
                md = __builtin_amdgcn_mfma_f32_16x16x32_f16(ah[m][1], bl1, md, 0, 0, 0);
#pragma unroll
                for (int r = 0; r < 4; ++r) {
                    float cross = fmaf(md[r], INVS, hh[r]);
                    float dist  = fmaf(cross, -2.0f, e2v);
                    int s = m * 4 + r;
                    float od1 = d1[s], od2 = d2[s];
                    unsigned int otp = tp[s];
                    bool lt1 = dist < od1;
                    bool lt2 = dist < od2;
                    float nd2 = lt2 ? dist : od2;
                    d2[s] = lt1 ? od1 : nd2;
                    unsigned int v1 = ((unsigned int)tg << 16) | (otp >> 16);
                    unsigned int v2 = (otp & 0xFFFF0000u) | (unsigned int)tg;
                    unsigned int ntp = lt2 ? v2 : otp;
                    tp[s] = lt1 ? v1 : ntp;
                    d1[s] = lt1 ? dist : od1;
                }
            }
        }
    }

    // ---- cross-lane merge of sorted pairs over the 16 col-lanes (within wave) ----
#pragma unroll
    for (int s = 0; s < 16; ++s) {
        float b1 = d1[s], b2 = d2[s];
        int t1 = (int)(tp[s] >> 16), t2 = (int)(tp[s] & 0xFFFFu);
#pragma unroll
        for (int xm = 1; xm < 16; xm <<= 1) {
            float o1 = __shfl_xor(b1, xm, 64);
            float o2 = __shfl_xor(b2, xm, 64);
            int   p1 = __shfl_xor(t1, xm, 64);
            int   p2 = __shfl_xor(t2, xm, 64);
            bool c1 = o1 < b1;
            float w1 = c1 ? o1 : b1;  int u1 = c1 ? p1 : t1;
            float l1 = c1 ? b1 : o1;  int ul = c1 ? t1 : p1;
            bool c2 = o2 < b2;
            float mv = c2 ? o2 : b2;  int um = c2 ? p2 : t2;
            bool c3 = mv < l1;
            b1 = w1; t1 = u1;
            b2 = c3 ? mv : l1; t2 = c3 ? um : ul;
        }
        if (lrow == 0) {
            int m = s >> 2, r = s & 3;
            int row = q0 + wm * 64 + m * 16 + lkg * 4 + r;
            int list = chunk * 4 + wn * 2;               // per-(chunk,wn) lists: NO cross-wave race
            pidx[(size_t)list       * n + row] = k0 + t1;
            pidx[(size_t)(list + 1) * n + row] = k0 + t2;
        }
    }
}

// ---------- exact fp32 re-rank of NLIST candidates ----------
__global__ __launch_bounds__(256) void rerank_kernel(
    const float* __restrict__ x, const float* __restrict__ emb, const float* __restrict__ e2,
    const int* __restrict__ pidx, float* __restrict__ out_ind, int* __restrict__ idxf,
    float* __restrict__ counts, int n)
{
    int q = blockIdx.x * blockDim.x + threadIdx.x;
    if (q >= n) return;
    float4 xr[16];
    const float4* xp = reinterpret_cast<const float4*>(x + (size_t)q * D);
#pragma unroll
    for (int i = 0; i < 16; ++i) xr[i] = xp[i];

    float best = 3.4e38f;
    int   bk   = 0x7fffffff;
#pragma unroll 1
    for (int c = 0; c < NLIST; ++c) {
        int k = pidx[(size_t)c * n + q];
        const float4* ep = reinterpret_cast<const float4*>(emb + (size_t)k * D);
        float a0 = 0.f, a1 = 0.f, a2 = 0.f, a3 = 0.f;
#pragma unroll
        for (int i = 0; i < 16; ++i) {
            float4 e4 = ep[i];
            a0 = fmaf(xr[i].x, e4.x, a0);
            a1 = fmaf(xr[i].y, e4.y, a1);
            a2 = fmaf(xr[i].z, e4.z, a2);
            a3 = fmaf(xr[i].w, e4.w, a3);
        }
        float dot  = (a0 + a1) + (a2 + a3);
        float dist = fmaf(dot, -2.0f, e2[k]);
        if (dist < best || (dist == best && k < bk)) { best = dist; bk = k; }
    }
    out_ind[q] = (float)bk;
    idxf[q]    = bk;
    atomicAdd(counts + bk, 1.0f);
}

// ---------- gather quantize + scatter embed_sum ----------
__global__ void gather_scatter_kernel(const float* __restrict__ x, const float* __restrict__ emb,
                                      const int* __restrict__ idxf, float* __restrict__ quant,
                                      float* __restrict__ embed_sum, int n)
{
    int gid = blockIdx.x * blockDim.x + threadIdx.x;
    int q = gid >> 6;
    int d = gid & 63;
    if (q >= n) return;
    int k = idxf[q];
    quant[(size_t)q * D + d] = emb[(size_t)k * D + d];
    atomicAdd(embed_sum + (size_t)k * D + d, x[(size_t)q * D + d]);
}

// ---------- EMA cluster_size + total ----------
__global__ __launch_bounds__(256) void ema_cs_kernel(const float* __restrict__ cluster_size,
                                                     float* __restrict__ ncs, float* __restrict__ total_ws,
                                                     int K)
{
    __shared__ float red[256];
    float local = 0.f;
    for (int k = threadIdx.x; k < K; k += 256) {
        float v = cluster_size[k] * DECAYF + ncs[k] * OMDF;
        ncs[k] = v;
        local += v;
    }
    red[threadIdx.x] = local;
    __syncthreads();
    for (int s = 128; s > 0; s >>= 1) {
        if (threadIdx.x < s) red[threadIdx.x] += red[threadIdx.x + s];
        __syncthreads();
    }
    if (threadIdx.x == 0) total_ws[0] = red[0];
}

// ---------- EMA embed_avg + normalize (runs last; overwrites eh/el scratch) ----------
__global__ void ema_embed_kernel(const float* __restrict__ embed_avg,
                                 const float* __restrict__ ncs, const float* __restrict__ total_ws,
                                 float* __restrict__ nea, float* __restrict__ enorm, int K)
{
    int gid = blockIdx.x * blockDim.x + threadIdx.x;
    if (gid >= K * D) return;
    int k = gid >> 6;
    float total = total_ws[0];
    float v = embed_avg[gid] * DECAYF + nea[gid] * OMDF;
    nea[gid] = v;
    float c = ncs[k];
    float smoothed = (c + EPSF) / (total + (float)K * EPSF) * total;
    enorm[gid] = v / smoothed;
}

extern "C" void kernel_launch(void* const* d_in, const int* in_sizes, int n_in,
                              void* d_out, int out_size, void* d_ws, size_t ws_size,
                              hipStream_t stream) {
    const float* x            = (const float*)d_in[0];   // [n, 64]
    const float* emb          = (const float*)d_in[1];   // [K, 64]
    const float* cluster_size = (const float*)d_in[2];   // [K]
    const float* embed_avg    = (const float*)d_in[3];   // [K, 64]

    const int n = in_sizes[0] / D;   // 16384
    const int K = in_sizes[1] / D;   // 8192

    // output layout (fp32): quantize | embed_ind | embed_normalized | new_cluster_size | new_embed_avg
    float* out     = (float*)d_out;
    float* quant   = out;                        // n*D
    float* out_ind = quant + (size_t)n * D;      // n
    float* enorm   = out_ind + n;                // K*D  (scratch for eh/el until final kernel)
    float* ncs     = enorm + (size_t)K * D;      // K
    float* nea     = ncs + K;                    // K*D

    f16* eh = reinterpret_cast<f16*>(enorm);     // K*D f16
    f16* el = eh + (size_t)K * D;                // K*D f16

    // workspace: e2 | pidx[NLIST][n] | idxf[n] | total
    float* e2    = (float*)d_ws;                       // K
    int*   pidx  = (int*)(e2 + K);                     // NLIST*n
    int*   idxf  = pidx + (size_t)NLIST * n;           // n
    float* total = (float*)(idxf + n);                 // 1

    hipMemsetAsync(ncs, 0, (size_t)K * sizeof(float), stream);
    hipMemsetAsync(nea, 0, (size_t)K * D * sizeof(float), stream);

    convertB_kernel<<<(K * D / 4 + 255) / 256, 256, 0, stream>>>(emb, eh, el, K * D / 4);
    e2_kernel<<<(K + 255) / 256, 256, 0, stream>>>(emb, e2, K);
    argmin_kernel<<<(n / BM) * NCHUNK, 256, 0, stream>>>(x, eh, el, e2, pidx, n, K);
    rerank_kernel<<<(n + 255) / 256, 256, 0, stream>>>(x, emb, e2, pidx, out_ind, idxf, ncs, n);
    gather_scatter_kernel<<<((size_t)n * D + 255) / 256, 256, 0, stream>>>(x, emb, idxf, quant, nea, n);
    ema_cs_kernel<<<1, 256, 0, stream>>>(cluster_size, ncs, total, K);
    ema_embed_kernel<<<(K * D + 255) / 256, 256, 0, stream>>>(embed_avg, ncs, total, nea, enorm, K);
}

// Round 6
// 179.748 us; speedup vs baseline: 3.1674x; 1.2353x over previous
//
#include <hip/hip_runtime.h>

#define D 64
#define BM 128        // queries per block (held in registers)
#define BN 64         // codes per LDS tile
#define NCHUNK 8      // K split across blocks
#define NLIST (2 * NCHUNK)   // one winner list per (chunk, wn-wave)
#define DECAYF 0.8f
#define OMDF 0.2f
#define EPSF 1e-5f
#define INVS 4.8828125e-4f   // 2^-11

typedef _Float16 f16;
typedef _Float16 f16x8 __attribute__((ext_vector_type(8)));
typedef float f32x4 __attribute__((ext_vector_type(4)));

// ---------- prep: e2[k] (exact fp32, round-5 numeric order) + f16 hi/lo split ----------
__global__ __launch_bounds__(256) void prep_kernel(const float* __restrict__ emb,
    f16* __restrict__ eh, f16* __restrict__ el, float* __restrict__ e2, int K)
{
    int k = blockIdx.x * blockDim.x + threadIdx.x;
    if (k >= K) return;
    const float4* p = reinterpret_cast<const float4*>(emb + (size_t)k * D);
    uint4* ehp = reinterpret_cast<uint4*>(eh + (size_t)k * D);
    uint4* elp = reinterpret_cast<uint4*>(el + (size_t)k * D);
    float s0 = 0.f, s1 = 0.f, s2 = 0.f, s3 = 0.f;
#pragma unroll
    for (int c = 0; c < 8; ++c) {
        float4 a = p[2 * c], b = p[2 * c + 1];
        s0 += a.x * a.x; s1 += a.y * a.y; s2 += a.z * a.z; s3 += a.w * a.w;
        s0 += b.x * b.x; s1 += b.y * b.y; s2 += b.z * b.z; s3 += b.w * b.w;
        float t[8] = {a.x, a.y, a.z, a.w, b.x, b.y, b.z, b.w};
        union { f16 h[8]; uint4 u; } H, L;
#pragma unroll
        for (int j = 0; j < 8; ++j) {
            f16 h = (f16)t[j];
            H.h[j] = h;
            L.h[j] = (f16)((t[j] - (float)h) * 2048.0f);
        }
        ehp[c] = H.u;
        elp[c] = L.u;
    }
    e2[k] = (s0 + s1) + (s2 + s3);
}

// ---------- MFMA 3-pass split-f16 + pair-max + top-1 per (chunk,wn) ----------
// 4 waves = 2(wm) x 2(wn). LDS tiles unpadded 128B rows, XOR slot swizzle.
__global__ __launch_bounds__(256, 2) void argmin_kernel(
    const float* __restrict__ x, const f16* __restrict__ eh, const f16* __restrict__ el,
    const float* __restrict__ e2, int* __restrict__ pidx, int n, int K)
{
    __shared__ f16 sh[2][BN * D];    // 2 x 8KB
    __shared__ f16 sl[2][BN * D];    // 2 x 8KB
    __shared__ float se2[2][BN];

    const int tx   = threadIdx.x;
    const int lane = tx & 63;
    const int wid  = tx >> 6;
    const int wm   = wid >> 1, wn = wid & 1;
    const int lrow = lane & 15;
    const int lkg  = lane >> 4;

    const int chunk = blockIdx.x % NCHUNK;
    const int mblk  = blockIdx.x / NCHUNK;
    const int q0    = mblk * BM;
    const int kc    = K / NCHUNK;    // 1024
    const int k0    = chunk * kc;
    const int NT    = kc / BN;       // 16

    // ---- A fragments: fp32 x rows -> f16 hi/lo in registers ----
    f16x8 ah[4][2], al[4][2];
#pragma unroll
    for (int m = 0; m < 4; ++m)
#pragma unroll
        for (int ks = 0; ks < 2; ++ks) {
            int row = q0 + wm * 64 + m * 16 + lrow;
            const float4* p = reinterpret_cast<const float4*>(
                x + (size_t)row * D + ks * 32 + lkg * 8);
            float4 va = p[0], vb = p[1];
            float t[8] = {va.x, va.y, va.z, va.w, vb.x, vb.y, vb.z, vb.w};
#pragma unroll
            for (int j = 0; j < 8; ++j) {
                f16 h = (f16)t[j];
                ah[m][ks][j] = h;
                al[m][ks][j] = (f16)((t[j] - (float)h) * 2048.0f);
            }
        }

    // ---- precomputed swizzled LDS offsets (f16 units), lane-constant ----
    int woff0, woff1;
    {
        int c0i = tx, c1i = tx + 256;
        int r0 = c0i >> 3, sl0 = c0i & 7;
        int r1 = c1i >> 3, sl1 = c1i & 7;
        woff0 = r0 * 64 + ((sl0 ^ (r0 & 7)) << 3);
        woff1 = r1 * 64 + ((sl1 ^ (r1 & 7)) << 3);
    }
    int roff[2][2];
#pragma unroll
    for (int nf = 0; nf < 2; ++nf)
#pragma unroll
        for (int ks = 0; ks < 2; ++ks) {
            int brow = wn * 32 + nf * 16 + lrow;
            roff[nf][ks] = brow * 64 + (((ks * 4 + lkg) ^ (brow & 7)) << 3);
        }

    // ---- top-1 state per C-slot (maximize s = cross - 0.5*e2) ----
    float dbest[16];
    int   tbest[16];
#pragma unroll
    for (int s = 0; s < 16; ++s) { dbest[s] = -3.4e38f; tbest[s] = 0; }

    // ---- prefetch tile 0 ----
    float4 ph[2], pl[2];
    float  pe2 = 0.f;
    {
        const float4* gh = reinterpret_cast<const float4*>(eh + (size_t)k0 * D);
        const float4* gl = reinterpret_cast<const float4*>(el + (size_t)k0 * D);
#pragma unroll
        for (int i = 0; i < 2; ++i) { ph[i] = gh[tx + 256 * i]; pl[i] = gl[tx + 256 * i]; }
        if (tx < BN) pe2 = e2[k0 + tx];
    }

#pragma unroll 1
    for (int tt = 0; tt < NT; ++tt) {
        const int cur = tt & 1;
        *reinterpret_cast<float4*>(&sh[cur][woff0]) = ph[0];
        *reinterpret_cast<float4*>(&sh[cur][woff1]) = ph[1];
        *reinterpret_cast<float4*>(&sl[cur][woff0]) = pl[0];
        *reinterpret_cast<float4*>(&sl[cur][woff1]) = pl[1];
        if (tx < BN) se2[cur][tx] = pe2;
        if (tt + 1 < NT) {
            int kt = k0 + (tt + 1) * BN;
            const float4* gh = reinterpret_cast<const float4*>(eh + (size_t)kt * D);
            const float4* gl = reinterpret_cast<const float4*>(el + (size_t)kt * D);
#pragma unroll
            for (int i = 0; i < 2; ++i) { ph[i] = gh[tx + 256 * i]; pl[i] = gl[tx + 256 * i]; }
            if (tx < BN) pe2 = e2[kt + tx];
        }
        __syncthreads();

        // ---- B fragments (swizzled reads: 2-way max, free) ----
        f16x8 bh[2][2], bl[2][2];
#pragma unroll
        for (int nf = 0; nf < 2; ++nf)
#pragma unroll
            for (int ks = 0; ks < 2; ++ks) {
                bh[nf][ks] = *reinterpret_cast<const f16x8*>(&sh[cur][roff[nf][ks]]);
                bl[nf][ks] = *reinterpret_cast<const f16x8*>(&sl[cur][roff[nf][ks]]);
            }
        const float c0 = -0.5f * se2[cur][wn * 32 + lrow];
        const float c1 = -0.5f * se2[cur][wn * 32 + 16 + lrow];
        const int   tg0 = tt * 2;

#pragma unroll
        for (int m = 0; m < 4; ++m) {
            f32x4 hh0 = {c0, c0, c0, c0}, md0 = {0.f, 0.f, 0.f, 0.f};
            f32x4 hh1 = {c1, c1, c1, c1}, md1 = {0.f, 0.f, 0.f, 0.f};
            hh0 = __builtin_amdgcn_mfma_f32_16x16x32_f16(ah[m][0], bh[0][0], hh0, 0, 0, 0);
            hh0 = __builtin_amdgcn_mfma_f32_16x16x32_f16(ah[m][1], bh[0][1], hh0, 0, 0, 0);
            md0 = __builtin_amdgcn_mfma_f32_16x16x32_f16(al[m][0], bh[0][0], md0, 0, 0, 0);
            md0 = __builtin_amdgcn_mfma_f32_16x16x32_f16(al[m][1], bh[0][1], md0, 0, 0, 0);
            md0 = __builtin_amdgcn_mfma_f32_16x16x32_f16(ah[m][0], bl[0][0], md0, 0, 0, 0);
            md0 = __builtin_amdgcn_mfma_f32_16x16x32_f16(ah[m][1], bl[0][1], md0, 0, 0, 0);
            hh1 = __builtin_amdgcn_mfma_f32_16x16x32_f16(ah[m][0], bh[1][0], hh1, 0, 0, 0);
            hh1 = __builtin_amdgcn_mfma_f32_16x16x32_f16(ah[m][1], bh[1][1], hh1, 0, 0, 0);
            md1 = __builtin_amdgcn_mfma_f32_16x16x32_f16(al[m][0], bh[1][0], md1, 0, 0, 0);
            md1 = __builtin_amdgcn_mfma_f32_16x16x32_f16(al[m][1], bh[1][1], md1, 0, 0, 0);
            md1 = __builtin_amdgcn_mfma_f32_16x16x32_f16(ah[m][0], bl[1][0], md1, 0, 0, 0);
            md1 = __builtin_amdgcn_mfma_f32_16x16x32_f16(ah[m][1], bl[1][1], md1, 0, 0, 0);
#pragma unroll
            for (int r = 0; r < 4; ++r) {
                float sA = fmaf(md0[r], INVS, hh0[r]);   // score code (tt, nf=0, lrow)
                float sB = fmaf(md1[r], INVS, hh1[r]);   // score code (tt, nf=1, lrow)
                bool cp = sB > sA;                       // strict: tie keeps lower nf
                float w = cp ? sB : sA;
                int   wt = tg0 + (cp ? 1 : 0);
                int s = m * 4 + r;
                bool cb = w > dbest[s];                  // strict: tie keeps earlier (lower tt)
                dbest[s] = cb ? w : dbest[s];
                tbest[s] = cb ? wt : tbest[s];
            }
        }
    }

    // ---- merge across the 16 col-lanes (argmax s; tie -> lower code id) ----
#pragma unroll
    for (int s = 0; s < 16; ++s) {
        float v = dbest[s];
        int cid = ((tbest[s] >> 1) << 6) | ((tbest[s] & 1) << 4) | (wn << 5) | lrow;
#pragma unroll
        for (int xm = 1; xm < 16; xm <<= 1) {
            float ov = __shfl_xor(v, xm, 64);
            int   oc = __shfl_xor(cid, xm, 64);
            if (ov > v || (ov == v && oc < cid)) { v = ov; cid = oc; }
        }
        if (lrow == 0) {
            int m = s >> 2, r = s & 3;
            int row = q0 + wm * 64 + m * 16 + lkg * 4 + r;
            pidx[(size_t)(chunk * 2 + wn) * n + row] = k0 + cid;
        }
    }
}

// ---------- exact fp32 re-rank of NLIST candidates ----------
__global__ __launch_bounds__(256) void rerank_kernel(
    const float* __restrict__ x, const float* __restrict__ emb, const float* __restrict__ e2,
    const int* __restrict__ pidx, float* __restrict__ out_ind, int* __restrict__ idxf,
    float* __restrict__ counts, int n)
{
    int q = blockIdx.x * blockDim.x + threadIdx.x;
    if (q >= n) return;
    float4 xr[16];
    const float4* xp = reinterpret_cast<const float4*>(x + (size_t)q * D);
#pragma unroll
    for (int i = 0; i < 16; ++i) xr[i] = xp[i];

    float best = 3.4e38f;
    int   bk   = 0x7fffffff;
#pragma unroll 1
    for (int c = 0; c < NLIST; ++c) {
        int k = pidx[(size_t)c * n + q];
        const float4* ep = reinterpret_cast<const float4*>(emb + (size_t)k * D);
        float a0 = 0.f, a1 = 0.f, a2 = 0.f, a3 = 0.f;
#pragma unroll
        for (int i = 0; i < 16; ++i) {
            float4 e4 = ep[i];
            a0 = fmaf(xr[i].x, e4.x, a0);
            a1 = fmaf(xr[i].y, e4.y, a1);
            a2 = fmaf(xr[i].z, e4.z, a2);
            a3 = fmaf(xr[i].w, e4.w, a3);
        }
        float dot  = (a0 + a1) + (a2 + a3);
        float dist = fmaf(dot, -2.0f, e2[k]);
        if (dist < best || (dist == best && k < bk)) { best = dist; bk = k; }
    }
    out_ind[q] = (float)bk;
    idxf[q]    = bk;
    atomicAdd(counts + bk, 1.0f);
}

// ---------- gather quantize + scatter embed_sum (wave per query) ----------
__global__ void gather_scatter_kernel(const float* __restrict__ x, const float* __restrict__ emb,
                                      const int* __restrict__ idxf, float* __restrict__ quant,
                                      float* __restrict__ embed_sum, int n)
{
    int gid = blockIdx.x * blockDim.x + threadIdx.x;
    int q = gid >> 6;
    int d = gid & 63;
    if (q >= n) return;
    int k = idxf[q];
    quant[(size_t)q * D + d] = emb[(size_t)k * D + d];
    atomicAdd(embed_sum + (size_t)k * D + d, x[(size_t)q * D + d]);
}

// ---------- EMA cluster_size (multi-block) + atomic total ----------
__global__ __launch_bounds__(256) void ema_cs_kernel(const float* __restrict__ cluster_size,
                                                     float* __restrict__ ncs, float* __restrict__ total_ws,
                                                     int K)
{
    int k = blockIdx.x * blockDim.x + threadIdx.x;
    float v = 0.f;
    if (k < K) {
        v = cluster_size[k] * DECAYF + ncs[k] * OMDF;
        ncs[k] = v;
    }
#pragma unroll
    for (int m = 1; m < 64; m <<= 1) v += __shfl_xor(v, m, 64);
    __shared__ float red[4];
    int lane = threadIdx.x & 63, w = threadIdx.x >> 6;
    if (lane == 0) red[w] = v;
    __syncthreads();
    if (threadIdx.x == 0) {
        float t = red[0] + red[1] + red[2] + red[3];
        atomicAdd(total_ws, t);
    }
}

// ---------- EMA embed_avg + normalize (runs last; overwrites eh/el scratch) ----------
__global__ void ema_embed_kernel(const float* __restrict__ embed_avg,
                                 const float* __restrict__ ncs, const float* __restrict__ total_ws,
                                 float* __restrict__ nea, float* __restrict__ enorm, int K)
{
    int gid = blockIdx.x * blockDim.x + threadIdx.x;
    if (gid >= K * D) return;
    int k = gid >> 6;
    float total = total_ws[0];
    float v = embed_avg[gid] * DECAYF + nea[gid] * OMDF;
    nea[gid] = v;
    float c = ncs[k];
    float smoothed = (c + EPSF) / (total + (float)K * EPSF) * total;
    enorm[gid] = v / smoothed;
}

extern "C" void kernel_launch(void* const* d_in, const int* in_sizes, int n_in,
                              void* d_out, int out_size, void* d_ws, size_t ws_size,
                              hipStream_t stream) {
    const float* x            = (const float*)d_in[0];   // [n, 64]
    const float* emb          = (const float*)d_in[1];   // [K, 64]
    const float* cluster_size = (const float*)d_in[2];   // [K]
    const float* embed_avg    = (const float*)d_in[3];   // [K, 64]

    const int n = in_sizes[0] / D;   // 16384
    const int K = in_sizes[1] / D;   // 8192

    // output layout (fp32): quantize | embed_ind | embed_normalized | new_cluster_size | new_embed_avg
    float* out     = (float*)d_out;
    float* quant   = out;                        // n*D
    float* out_ind = quant + (size_t)n * D;      // n
    float* enorm   = out_ind + n;                // K*D  (scratch for eh/el until final kernel)
    float* ncs     = enorm + (size_t)K * D;      // K
    float* nea     = ncs + K;                    // K*D

    f16* eh = reinterpret_cast<f16*>(enorm);     // K*D f16
    f16* el = eh + (size_t)K * D;                // K*D f16

    // workspace: e2 | pidx[NLIST][n] | idxf[n] | total
    float* e2    = (float*)d_ws;                       // K
    int*   pidx  = (int*)(e2 + K);                     // NLIST*n
    int*   idxf  = pidx + (size_t)NLIST * n;           // n
    float* total = (float*)(idxf + n);                 // 1

    hipMemsetAsync(ncs, 0, (size_t)K * sizeof(float), stream);
    hipMemsetAsync(nea, 0, (size_t)K * D * sizeof(float), stream);
    hipMemsetAsync(total, 0, sizeof(float), stream);

    prep_kernel<<<(K + 255) / 256, 256, 0, stream>>>(emb, eh, el, e2, K);
    argmin_kernel<<<(n / BM) * NCHUNK, 256, 0, stream>>>(x, eh, el, e2, pidx, n, K);
    rerank_kernel<<<(n + 255) / 256, 256, 0, stream>>>(x, emb, e2, pidx, out_ind, idxf, ncs, n);
    gather_scatter_kernel<<<((size_t)n * D + 255) / 256, 256, 0, stream>>>(x, emb, idxf, quant, nea, n);
    ema_cs_kernel<<<(K + 255) / 256, 256, 0, stream>>>(cluster_size, ncs, total, K);
    ema_embed_kernel<<<(K * D + 255) / 256, 256, 0, stream>>>(embed_avg, ncs, total, nea, enorm, K);
}

// Round 7
// 173.789 us; speedup vs baseline: 3.2760x; 1.0343x over previous
//
#include <hip/hip_runtime.h>

#define D 64
#define BM 128        // queries per block (held in registers)
#define BN 64         // codes per LDS tile
#define NCHUNK 8      // K split across blocks
#define NLIST (2 * NCHUNK)   // one winner list per (chunk, wn-wave)
#define DECAYF 0.8f
#define OMDF 0.2f
#define EPSF 1e-5f
#define INVS 4.8828125e-4f   // 2^-11

typedef _Float16 f16;
typedef _Float16 f16x8 __attribute__((ext_vector_type(8)));
typedef float f32x4 __attribute__((ext_vector_type(4)));

// ---------- prep: e2[k] (exact fp32) + f16 hi/lo split; 64-thread blocks ----------
__global__ __launch_bounds__(64) void prep_kernel(const float* __restrict__ emb,
    f16* __restrict__ eh, f16* __restrict__ el, float* __restrict__ e2, int K)
{
    int k = blockIdx.x * blockDim.x + threadIdx.x;
    if (k >= K) return;
    const float4* p = reinterpret_cast<const float4*>(emb + (size_t)k * D);
    uint4* ehp = reinterpret_cast<uint4*>(eh + (size_t)k * D);
    uint4* elp = reinterpret_cast<uint4*>(el + (size_t)k * D);
    float s0 = 0.f, s1 = 0.f, s2 = 0.f, s3 = 0.f;
#pragma unroll
    for (int c = 0; c < 8; ++c) {
        float4 a = p[2 * c], b = p[2 * c + 1];
        s0 += a.x * a.x; s1 += a.y * a.y; s2 += a.z * a.z; s3 += a.w * a.w;
        s0 += b.x * b.x; s1 += b.y * b.y; s2 += b.z * b.z; s3 += b.w * b.w;
        float t[8] = {a.x, a.y, a.z, a.w, b.x, b.y, b.z, b.w};
        union { f16 h[8]; uint4 u; } H, L;
#pragma unroll
        for (int j = 0; j < 8; ++j) {
            f16 h = (f16)t[j];
            H.h[j] = h;
            L.h[j] = (f16)((t[j] - (float)h) * 2048.0f);
        }
        ehp[c] = H.u;
        elp[c] = L.u;
    }
    e2[k] = (s0 + s1) + (s2 + s3);
}

// ---------- MFMA 3-pass split-f16 + packed-uint top-1 per (chunk,wn) ----------
// 4 waves = 2(wm) x 2(wn). Prefetch issued AFTER the barrier so the compiler's
// vmcnt(0)-drain at s_barrier never waits on fresh loads (m97 stall fix).
__global__ __launch_bounds__(256, 3) void argmin_kernel(
    const float* __restrict__ x, const f16* __restrict__ eh, const f16* __restrict__ el,
    const float* __restrict__ e2, int* __restrict__ pidx, int n, int K)
{
    __shared__ f16 sh[2][BN * D];    // 2 x 8KB
    __shared__ f16 sl[2][BN * D];    // 2 x 8KB
    __shared__ float se2a[1024];     // whole-chunk -0.5*e2 (4KB)

    const int tx   = threadIdx.x;
    const int lane = tx & 63;
    const int wid  = tx >> 6;
    const int wm   = wid >> 1, wn = wid & 1;
    const int lrow = lane & 15;
    const int lkg  = lane >> 4;

    const int chunk = blockIdx.x % NCHUNK;
    const int mblk  = blockIdx.x / NCHUNK;
    const int q0    = mblk * BM;
    const int kc    = K / NCHUNK;    // 1024
    const int k0    = chunk * kc;
    const int NT    = kc / BN;       // 16

    // ---- A fragments: fp32 x rows -> f16 hi/lo in registers ----
    f16x8 ah[4][2], al[4][2];
#pragma unroll
    for (int m = 0; m < 4; ++m)
#pragma unroll
        for (int ks = 0; ks < 2; ++ks) {
            int row = q0 + wm * 64 + m * 16 + lrow;
            const float4* p = reinterpret_cast<const float4*>(
                x + (size_t)row * D + ks * 32 + lkg * 8);
            float4 va = p[0], vb = p[1];
            float t[8] = {va.x, va.y, va.z, va.w, vb.x, vb.y, vb.z, vb.w};
#pragma unroll
            for (int j = 0; j < 8; ++j) {
                f16 h = (f16)t[j];
                ah[m][ks][j] = h;
                al[m][ks][j] = (f16)((t[j] - (float)h) * 2048.0f);
            }
        }

    // ---- whole-chunk e2 table, prescaled by -0.5 (covered by iter-0 barrier) ----
    for (int i = tx; i < kc; i += 256) se2a[i] = -0.5f * e2[k0 + i];

    // ---- precomputed swizzled LDS offsets (f16 units), lane-constant ----
    int woff0, woff1;
    {
        int r0 = tx >> 3,          sl0 = tx & 7;
        int r1 = (tx + 256) >> 3,  sl1 = tx & 7;
        woff0 = r0 * 64 + ((sl0 ^ (r0 & 7)) << 3);
        woff1 = r1 * 64 + ((sl1 ^ (r1 & 7)) << 3);
    }
    int roff[2][2];
#pragma unroll
    for (int nf = 0; nf < 2; ++nf)
#pragma unroll
        for (int ks = 0; ks < 2; ++ks) {
            int brow = wn * 32 + nf * 16 + lrow;
            roff[nf][ks] = brow * 64 + (((ks * 4 + lkg) ^ (brow & 7)) << 3);
        }

    // ---- packed top-1 state per C-slot: sortable-uint score | 5-bit tag ----
    unsigned int pbest[16];
#pragma unroll
    for (int s = 0; s < 16; ++s) pbest[s] = 0u;

    // ---- prefetch tile 0 (one-time stall) ----
    float4 ph[2], pl[2];
    {
        const float4* gh = reinterpret_cast<const float4*>(eh + (size_t)k0 * D);
        const float4* gl = reinterpret_cast<const float4*>(el + (size_t)k0 * D);
        ph[0] = gh[tx]; ph[1] = gh[tx + 256];
        pl[0] = gl[tx]; pl[1] = gl[tx + 256];
    }

#pragma unroll 1
    for (int tt = 0; tt < NT; ++tt) {
        const int cur = tt & 1;
        *reinterpret_cast<float4*>(&sh[cur][woff0]) = ph[0];
        *reinterpret_cast<float4*>(&sh[cur][woff1]) = ph[1];
        *reinterpret_cast<float4*>(&sl[cur][woff0]) = pl[0];
        *reinterpret_cast<float4*>(&sl[cur][woff1]) = pl[1];
        __syncthreads();

        // issue next tile's loads AFTER the barrier: a full compute phase hides
        // them, and the next barrier's vmcnt-drain finds them already consumed.
        if (tt + 1 < NT) {
            int kt = k0 + (tt + 1) * BN;
            const float4* gh = reinterpret_cast<const float4*>(eh + (size_t)kt * D);
            const float4* gl = reinterpret_cast<const float4*>(el + (size_t)kt * D);
            ph[0] = gh[tx]; ph[1] = gh[tx + 256];
            pl[0] = gl[tx]; pl[1] = gl[tx + 256];
        }

        // ---- B fragments (swizzled reads: <=2-way, free) ----
        f16x8 bh[2][2], bl[2][2];
#pragma unroll
        for (int nf = 0; nf < 2; ++nf)
#pragma unroll
            for (int ks = 0; ks < 2; ++ks) {
                bh[nf][ks] = *reinterpret_cast<const f16x8*>(&sh[cur][roff[nf][ks]]);
                bl[nf][ks] = *reinterpret_cast<const f16x8*>(&sl[cur][roff[nf][ks]]);
            }
        const float c0 = se2a[tt * 64 + wn * 32 + lrow];
        const float c1 = se2a[tt * 64 + wn * 32 + 16 + lrow];
        const unsigned int tagA = (unsigned int)(tt * 2);
        const unsigned int tagB = tagA + 1u;

#pragma unroll
        for (int m = 0; m < 4; ++m) {
            f32x4 hh0 = {c0, c0, c0, c0}, md0 = {0.f, 0.f, 0.f, 0.f};
            f32x4 hh1 = {c1, c1, c1, c1}, md1 = {0.f, 0.f, 0.f, 0.f};
            hh0 = __builtin_amdgcn_mfma_f32_16x16x32_f16(ah[m][0], bh[0][0], hh0, 0, 0, 0);
            hh0 = __builtin_amdgcn_mfma_f32_16x16x32_f16(ah[m][1], bh[0][1], hh0, 0, 0, 0);
            md0 = __builtin_amdgcn_mfma_f32_16x16x32_f16(al[m][0], bh[0][0], md0, 0, 0, 0);
            md0 = __builtin_amdgcn_mfma_f32_16x16x32_f16(al[m][1], bh[0][1], md0, 0, 0, 0);
            md0 = __builtin_amdgcn_mfma_f32_16x16x32_f16(ah[m][0], bl[0][0], md0, 0, 0, 0);
            md0 = __builtin_amdgcn_mfma_f32_16x16x32_f16(ah[m][1], bl[0][1], md0, 0, 0, 0);
            hh1 = __builtin_amdgcn_mfma_f32_16x16x32_f16(ah[m][0], bh[1][0], hh1, 0, 0, 0);
            hh1 = __builtin_amdgcn_mfma_f32_16x16x32_f16(ah[m][1], bh[1][1], hh1, 0, 0, 0);
            md1 = __builtin_amdgcn_mfma_f32_16x16x32_f16(al[m][0], bh[1][0], md1, 0, 0, 0);
            md1 = __builtin_amdgcn_mfma_f32_16x16x32_f16(al[m][1], bh[1][1], md1, 0, 0, 0);
            md1 = __builtin_amdgcn_mfma_f32_16x16x32_f16(ah[m][0], bl[1][0], md1, 0, 0, 0);
            md1 = __builtin_amdgcn_mfma_f32_16x16x32_f16(ah[m][1], bl[1][1], md1, 0, 0, 0);
#pragma unroll
            for (int r = 0; r < 4; ++r) {
                float sA = fmaf(md0[r], INVS, hh0[r]);   // score code (tt, nf=0, lrow)
                float sB = fmaf(md1[r], INVS, hh1[r]);   // score code (tt, nf=1, lrow)
                unsigned int bA = __float_as_uint(sA);
                unsigned int bB = __float_as_uint(sB);
                unsigned int uA = bA ^ (0x80000000u | (unsigned int)((int)bA >> 31));
                unsigned int uB = bB ^ (0x80000000u | (unsigned int)((int)bB >> 31));
                unsigned int wA = (uA & 0xFFFFFFE0u) | tagA;
                unsigned int wB = (uB & 0xFFFFFFE0u) | tagB;
                unsigned int w  = wA > wB ? wA : wB;
                int s = m * 4 + r;
                pbest[s] = pbest[s] > w ? pbest[s] : w;
            }
        }
    }

    // ---- merge across the 16 col-lanes (argmax packed; tie -> lower code id) ----
#pragma unroll
    for (int s = 0; s < 16; ++s) {
        unsigned int u = pbest[s];
        unsigned int tag = u & 31u;
        int cid = (int)((tag >> 1) << 6) | (int)((tag & 1u) << 4) | (wn << 5) | lrow;
#pragma unroll
        for (int xm = 1; xm < 16; xm <<= 1) {
            unsigned int ou = __shfl_xor(u, xm, 64);
            int          oc = __shfl_xor(cid, xm, 64);
            if (ou > u || (ou == u && oc < cid)) { u = ou; cid = oc; }
        }
        if (lrow == 0) {
            int m = s >> 2, r = s & 3;
            int row = q0 + wm * 64 + m * 16 + lkg * 4 + r;
            pidx[(size_t)(chunk * 2 + wn) * n + row] = k0 + cid;
        }
    }
}

// ---------- exact fp32 re-rank of NLIST candidates ----------
__global__ __launch_bounds__(256) void rerank_kernel(
    const float* __restrict__ x, const float* __restrict__ emb, const float* __restrict__ e2,
    const int* __restrict__ pidx, float* __restrict__ out_ind, int* __restrict__ idxf,
    float* __restrict__ counts, int n)
{
    int q = blockIdx.x * blockDim.x + threadIdx.x;
    if (q >= n) return;
    float4 xr[16];
    const float4* xp = reinterpret_cast<const float4*>(x + (size_t)q * D);
#pragma unroll
    for (int i = 0; i < 16; ++i) xr[i] = xp[i];

    float best = 3.4e38f;
    int   bk   = 0x7fffffff;
#pragma unroll 1
    for (int c = 0; c < NLIST; ++c) {
        int k = pidx[(size_t)c * n + q];
        const float4* ep = reinterpret_cast<const float4*>(emb + (size_t)k * D);
        float a0 = 0.f, a1 = 0.f, a2 = 0.f, a3 = 0.f;
#pragma unroll
        for (int i = 0; i < 16; ++i) {
            float4 e4 = ep[i];
            a0 = fmaf(xr[i].x, e4.x, a0);
            a1 = fmaf(xr[i].y, e4.y, a1);
            a2 = fmaf(xr[i].z, e4.z, a2);
            a3 = fmaf(xr[i].w, e4.w, a3);
        }
        float dot  = (a0 + a1) + (a2 + a3);
        float dist = fmaf(dot, -2.0f, e2[k]);
        if (dist < best || (dist == best && k < bk)) { best = dist; bk = k; }
    }
    out_ind[q] = (float)bk;
    idxf[q]    = bk;
    atomicAdd(counts + bk, 1.0f);
}

// ---------- gather quantize + scatter embed_sum (wave per query) ----------
__global__ void gather_scatter_kernel(const float* __restrict__ x, const float* __restrict__ emb,
                                      const int* __restrict__ idxf, float* __restrict__ quant,
                                      float* __restrict__ embed_sum, int n)
{
    int gid = blockIdx.x * blockDim.x + threadIdx.x;
    int q = gid >> 6;
    int d = gid & 63;
    if (q >= n) return;
    int k = idxf[q];
    quant[(size_t)q * D + d] = emb[(size_t)k * D + d];
    atomicAdd(embed_sum + (size_t)k * D + d, x[(size_t)q * D + d]);
}

// ---------- EMA cluster_size (multi-block) + atomic total ----------
__global__ __launch_bounds__(256) void ema_cs_kernel(const float* __restrict__ cluster_size,
                                                     float* __restrict__ ncs, float* __restrict__ total_ws,
                                                     int K)
{
    int k = blockIdx.x * blockDim.x + threadIdx.x;
    float v = 0.f;
    if (k < K) {
        v = cluster_size[k] * DECAYF + ncs[k] * OMDF;
        ncs[k] = v;
    }
#pragma unroll
    for (int m = 1; m < 64; m <<= 1) v += __shfl_xor(v, m, 64);
    __shared__ float red[4];
    int lane = threadIdx.x & 63, w = threadIdx.x >> 6;
    if (lane == 0) red[w] = v;
    __syncthreads();
    if (threadIdx.x == 0) {
        float t = red[0] + red[1] + red[2] + red[3];
        atomicAdd(total_ws, t);
    }
}

// ---------- EMA embed_avg + normalize (runs last; overwrites eh/el scratch) ----------
__global__ void ema_embed_kernel(const float* __restrict__ embed_avg,
                                 const float* __restrict__ ncs, const float* __restrict__ total_ws,
                                 float* __restrict__ nea, float* __restrict__ enorm, int K)
{
    int gid = blockIdx.x * blockDim.x + threadIdx.x;
    if (gid >= K * D) return;
    int k = gid >> 6;
    float total = total_ws[0];
    float v = embed_avg[gid] * DECAYF + nea[gid] * OMDF;
    nea[gid] = v;
    float c = ncs[k];
    float smoothed = (c + EPSF) / (total + (float)K * EPSF) * total;
    enorm[gid] = v / smoothed;
}

extern "C" void kernel_launch(void* const* d_in, const int* in_sizes, int n_in,
                              void* d_out, int out_size, void* d_ws, size_t ws_size,
                              hipStream_t stream) {
    const float* x            = (const float*)d_in[0];   // [n, 64]
    const float* emb          = (const float*)d_in[1];   // [K, 64]
    const float* cluster_size = (const float*)d_in[2];   // [K]
    const float* embed_avg    = (const float*)d_in[3];   // [K, 64]

    const int n = in_sizes[0] / D;   // 16384
    const int K = in_sizes[1] / D;   // 8192

    // output layout (fp32): quantize | embed_ind | embed_normalized | new_cluster_size | new_embed_avg
    float* out     = (float*)d_out;
    float* quant   = out;                        // n*D
    float* out_ind = quant + (size_t)n * D;      // n
    float* enorm   = out_ind + n;                // K*D  (scratch for eh/el until final kernel)
    float* ncs     = enorm + (size_t)K * D;      // K
    float* nea     = ncs + K;                    // K*D

    f16* eh = reinterpret_cast<f16*>(enorm);     // K*D f16
    f16* el = eh + (size_t)K * D;                // K*D f16

    // workspace: e2 | pidx[NLIST][n] | idxf[n] | total
    float* e2    = (float*)d_ws;                       // K
    int*   pidx  = (int*)(e2 + K);                     // NLIST*n
    int*   idxf  = pidx + (size_t)NLIST * n;           // n
    float* total = (float*)(idxf + n);                 // 1

    hipMemsetAsync(ncs, 0, (size_t)K * sizeof(float), stream);
    hipMemsetAsync(nea, 0, (size_t)K * D * sizeof(float), stream);
    hipMemsetAsync(total, 0, sizeof(float), stream);

    prep_kernel<<<(K + 63) / 64, 64, 0, stream>>>(emb, eh, el, e2, K);
    argmin_kernel<<<(n / BM) * NCHUNK, 256, 0, stream>>>(x, eh, el, e2, pidx, n, K);
    rerank_kernel<<<(n + 255) / 256, 256, 0, stream>>>(x, emb, e2, pidx, out_ind, idxf, ncs, n);
    gather_scatter_kernel<<<((size_t)n * D + 255) / 256, 256, 0, stream>>>(x, emb, idxf, quant, nea, n);
    ema_cs_kernel<<<(K + 255) / 256, 256, 0, stream>>>(cluster_size, ncs, total, K);
    ema_embed_kernel<<<(K * D + 255) / 256, 256, 0, stream>>>(embed_avg, ncs, total, nea, enorm, K);
}

// Round 8
// 154.431 us; speedup vs baseline: 3.6866x; 1.1253x over previous
//
#include <hip/hip_runtime.h>

#define D 64
#define BM 128        // queries per block
#define NCHUNK 8      // K split across blocks
#define NLIST (2 * NCHUNK)   // one winner list per (chunk, wn-wave)
#define DECAYF 0.8f
#define OMDF 0.2f
#define EPSF 1e-5f
#define INVS 4.8828125e-4f   // 2^-11

typedef _Float16 f16;
typedef _Float16 f16x8 __attribute__((ext_vector_type(8)));
typedef float f32x4 __attribute__((ext_vector_type(4)));

// ---------- prep: e2[k] (exact fp32) + f16 hi/lo split ----------
__global__ __launch_bounds__(64) void prep_kernel(const float* __restrict__ emb,
    f16* __restrict__ eh, f16* __restrict__ el, float* __restrict__ e2, int K)
{
    int k = blockIdx.x * blockDim.x + threadIdx.x;
    if (k >= K) return;
    const float4* p = reinterpret_cast<const float4*>(emb + (size_t)k * D);
    uint4* ehp = reinterpret_cast<uint4*>(eh + (size_t)k * D);
    uint4* elp = reinterpret_cast<uint4*>(el + (size_t)k * D);
    float s0 = 0.f, s1 = 0.f, s2 = 0.f, s3 = 0.f;
#pragma unroll
    for (int c = 0; c < 8; ++c) {
        float4 a = p[2 * c], b = p[2 * c + 1];
        s0 += a.x * a.x; s1 += a.y * a.y; s2 += a.z * a.z; s3 += a.w * a.w;
        s0 += b.x * b.x; s1 += b.y * b.y; s2 += b.z * b.z; s3 += b.w * b.w;
        float t[8] = {a.x, a.y, a.z, a.w, b.x, b.y, b.z, b.w};
        union { f16 h[8]; uint4 u; } H, L;
#pragma unroll
        for (int j = 0; j < 8; ++j) {
            f16 h = (f16)t[j];
            H.h[j] = h;
            L.h[j] = (f16)((t[j] - (float)h) * 2048.0f);
        }
        ehp[c] = H.u;
        elp[c] = L.u;
    }
    e2[k] = (s0 + s1) + (s2 + s3);
}

// ---------- MFMA 3-pass split-f16, NO LDS tiles / NO in-loop barriers ----------
// B-fragments loaded per-wave straight from L2 (eh/el are 2MB, L2-resident),
// register double-buffered (2-stage manual pipeline, static names only).
__global__ __launch_bounds__(256, 2) void argmin_kernel(
    const float* __restrict__ x, const f16* __restrict__ eh, const f16* __restrict__ el,
    const float* __restrict__ e2, int* __restrict__ pidx, int n, int K)
{
    __shared__ float se2a[1024];     // whole-chunk -0.5*e2 (4KB)

    const int tx   = threadIdx.x;
    const int lane = tx & 63;
    const int wid  = tx >> 6;
    const int wm   = wid >> 1, wn = wid & 1;
    const int lrow = lane & 15;
    const int lkg  = lane >> 4;

    const int chunk = blockIdx.x % NCHUNK;
    const int mblk  = blockIdx.x / NCHUNK;
    const int q0    = mblk * BM;
    const int kc    = K / NCHUNK;    // 1024
    const int k0    = chunk * kc;
    const int NT    = kc / 64;       // 16 tiles of 64 codes

    // ---- A fragments: fp32 x rows -> f16 hi/lo in registers (64 VGPR) ----
    f16x8 ah[4][2], al[4][2];
#pragma unroll
    for (int m = 0; m < 4; ++m)
#pragma unroll
        for (int ks = 0; ks < 2; ++ks) {
            int row = q0 + wm * 64 + m * 16 + lrow;
            const float4* p = reinterpret_cast<const float4*>(
                x + (size_t)row * D + ks * 32 + lkg * 8);
            float4 va = p[0], vb = p[1];
            float t[8] = {va.x, va.y, va.z, va.w, vb.x, vb.y, vb.z, vb.w};
#pragma unroll
            for (int j = 0; j < 8; ++j) {
                f16 h = (f16)t[j];
                ah[m][ks][j] = h;
                al[m][ks][j] = (f16)((t[j] - (float)h) * 2048.0f);
            }
        }

    // ---- whole-chunk e2 table, prescaled by -0.5 ----
    for (int i = tx; i < kc; i += 256) se2a[i] = -0.5f * e2[k0 + i];
    __syncthreads();   // the ONLY barrier

    // ---- lane-constant global fragment offsets (f16 units) ----
    int ofs[2][2];
#pragma unroll
    for (int nf = 0; nf < 2; ++nf)
#pragma unroll
        for (int ks = 0; ks < 2; ++ks)
            ofs[nf][ks] = (wn * 32 + nf * 16 + lrow) * 64 + ks * 32 + lkg * 8;

    // ---- packed top-1 state per C-slot: sortable-uint score | 5-bit tag ----
    unsigned int pbest[16];
#pragma unroll
    for (int s = 0; s < 16; ++s) pbest[s] = 0u;

    auto LOADB = [&](f16x8 (&BH)[2][2], f16x8 (&BL)[2][2], int ttv) {
        const size_t kb = (size_t)(k0 + ttv * 64) * 64;
#pragma unroll
        for (int nf = 0; nf < 2; ++nf)
#pragma unroll
            for (int ks = 0; ks < 2; ++ks) {
                BH[nf][ks] = *reinterpret_cast<const f16x8*>(eh + kb + ofs[nf][ks]);
                BL[nf][ks] = *reinterpret_cast<const f16x8*>(el + kb + ofs[nf][ks]);
            }
    };

    auto COMPUTE = [&](const f16x8 (&BH)[2][2], const f16x8 (&BL)[2][2], int ttv) {
        const float c0 = se2a[ttv * 64 + wn * 32 + lrow];
        const float c1 = se2a[ttv * 64 + wn * 32 + 16 + lrow];
        const unsigned int tagA = (unsigned int)(ttv * 2);
        const unsigned int tagB = tagA + 1u;
#pragma unroll
        for (int m = 0; m < 4; ++m) {
            f32x4 hh0 = {c0, c0, c0, c0}, md0 = {0.f, 0.f, 0.f, 0.f};
            f32x4 hh1 = {c1, c1, c1, c1}, md1 = {0.f, 0.f, 0.f, 0.f};
            hh0 = __builtin_amdgcn_mfma_f32_16x16x32_f16(ah[m][0], BH[0][0], hh0, 0, 0, 0);
            hh1 = __builtin_amdgcn_mfma_f32_16x16x32_f16(ah[m][0], BH[1][0], hh1, 0, 0, 0);
            hh0 = __builtin_amdgcn_mfma_f32_16x16x32_f16(ah[m][1], BH[0][1], hh0, 0, 0, 0);
            hh1 = __builtin_amdgcn_mfma_f32_16x16x32_f16(ah[m][1], BH[1][1], hh1, 0, 0, 0);
            md0 = __builtin_amdgcn_mfma_f32_16x16x32_f16(al[m][0], BH[0][0], md0, 0, 0, 0);
            md1 = __builtin_amdgcn_mfma_f32_16x16x32_f16(al[m][0], BH[1][0], md1, 0, 0, 0);
            md0 = __builtin_amdgcn_mfma_f32_16x16x32_f16(al[m][1], BH[0][1], md0, 0, 0, 0);
            md1 = __builtin_amdgcn_mfma_f32_16x16x32_f16(al[m][1], BH[1][1], md1, 0, 0, 0);
            md0 = __builtin_amdgcn_mfma_f32_16x16x32_f16(ah[m][0], BL[0][0], md0, 0, 0, 0);
            md1 = __builtin_amdgcn_mfma_f32_16x16x32_f16(ah[m][0], BL[1][0], md1, 0, 0, 0);
            md0 = __builtin_amdgcn_mfma_f32_16x16x32_f16(ah[m][1], BL[0][1], md0, 0, 0, 0);
            md1 = __builtin_amdgcn_mfma_f32_16x16x32_f16(ah[m][1], BL[1][1], md1, 0, 0, 0);
#pragma unroll
            for (int r = 0; r < 4; ++r) {
                float sA = fmaf(md0[r], INVS, hh0[r]);
                float sB = fmaf(md1[r], INVS, hh1[r]);
                unsigned int bA = __float_as_uint(sA);
                unsigned int bB = __float_as_uint(sB);
                unsigned int uA = bA ^ (0x80000000u | (unsigned int)((int)bA >> 31));
                unsigned int uB = bB ^ (0x80000000u | (unsigned int)((int)bB >> 31));
                unsigned int wA = (uA & 0xFFFFFFE0u) | tagA;
                unsigned int wB = (uB & 0xFFFFFFE0u) | tagB;
                unsigned int w  = wA > wB ? wA : wB;
                int s = m * 4 + r;
                pbest[s] = pbest[s] > w ? pbest[s] : w;
            }
        }
    };

    // ---- 2-stage register pipeline: load(t+1) overlaps compute(t) ----
    f16x8 bh[2][2], bl[2][2], nh[2][2], nl[2][2];
    LOADB(bh, bl, 0);
#pragma unroll 1
    for (int tt = 0; tt < NT; tt += 2) {
        LOADB(nh, nl, tt + 1);           // NT even: tt+1 < NT always
        COMPUTE(bh, bl, tt);
        if (tt + 2 < NT) LOADB(bh, bl, tt + 2);
        COMPUTE(nh, nl, tt + 1);
    }

    // ---- merge across the 16 col-lanes (argmax packed; tie -> lower code id) ----
#pragma unroll
    for (int s = 0; s < 16; ++s) {
        unsigned int u = pbest[s];
        unsigned int tag = u & 31u;
        int cid = (int)((tag >> 1) << 6) | (int)((tag & 1u) << 4) | (wn << 5) | lrow;
#pragma unroll
        for (int xm = 1; xm < 16; xm <<= 1) {
            unsigned int ou = __shfl_xor(u, xm, 64);
            int          oc = __shfl_xor(cid, xm, 64);
            if (ou > u || (ou == u && oc < cid)) { u = ou; cid = oc; }
        }
        if (lrow == 0) {
            int m = s >> 2, r = s & 3;
            int row = q0 + wm * 64 + m * 16 + lkg * 4 + r;
            pidx[(size_t)(chunk * 2 + wn) * n + row] = k0 + cid;
        }
    }
}

// ---------- exact fp32 re-rank of NLIST candidates ----------
__global__ __launch_bounds__(256) void rerank_kernel(
    const float* __restrict__ x, const float* __restrict__ emb, const float* __restrict__ e2,
    const int* __restrict__ pidx, float* __restrict__ out_ind, int* __restrict__ idxf,
    float* __restrict__ counts, int n)
{
    int q = blockIdx.x * blockDim.x + threadIdx.x;
    if (q >= n) return;
    float4 xr[16];
    const float4* xp = reinterpret_cast<const float4*>(x + (size_t)q * D);
#pragma unroll
    for (int i = 0; i < 16; ++i) xr[i] = xp[i];

    float best = 3.4e38f;
    int   bk   = 0x7fffffff;
#pragma unroll 1
    for (int c = 0; c < NLIST; ++c) {
        int k = pidx[(size_t)c * n + q];
        const float4* ep = reinterpret_cast<const float4*>(emb + (size_t)k * D);
        float a0 = 0.f, a1 = 0.f, a2 = 0.f, a3 = 0.f;
#pragma unroll
        for (int i = 0; i < 16; ++i) {
            float4 e4 = ep[i];
            a0 = fmaf(xr[i].x, e4.x, a0);
            a1 = fmaf(xr[i].y, e4.y, a1);
            a2 = fmaf(xr[i].z, e4.z, a2);
            a3 = fmaf(xr[i].w, e4.w, a3);
        }
        float dot  = (a0 + a1) + (a2 + a3);
        float dist = fmaf(dot, -2.0f, e2[k]);
        if (dist < best || (dist == best && k < bk)) { best = dist; bk = k; }
    }
    out_ind[q] = (float)bk;
    idxf[q]    = bk;
    atomicAdd(counts + bk, 1.0f);
}

// ---------- gather quantize + scatter embed_sum (wave per query) ----------
__global__ void gather_scatter_kernel(const float* __restrict__ x, const float* __restrict__ emb,
                                      const int* __restrict__ idxf, float* __restrict__ quant,
                                      float* __restrict__ embed_sum, int n)
{
    int gid = blockIdx.x * blockDim.x + threadIdx.x;
    int q = gid >> 6;
    int d = gid & 63;
    if (q >= n) return;
    int k = idxf[q];
    quant[(size_t)q * D + d] = emb[(size_t)k * D + d];
    atomicAdd(embed_sum + (size_t)k * D + d, x[(size_t)q * D + d]);
}

// ---------- EMA cluster_size (multi-block) + atomic total ----------
__global__ __launch_bounds__(256) void ema_cs_kernel(const float* __restrict__ cluster_size,
                                                     float* __restrict__ ncs, float* __restrict__ total_ws,
                                                     int K)
{
    int k = blockIdx.x * blockDim.x + threadIdx.x;
    float v = 0.f;
    if (k < K) {
        v = cluster_size[k] * DECAYF + ncs[k] * OMDF;
        ncs[k] = v;
    }
#pragma unroll
    for (int m = 1; m < 64; m <<= 1) v += __shfl_xor(v, m, 64);
    __shared__ float red[4];
    int lane = threadIdx.x & 63, w = threadIdx.x >> 6;
    if (lane == 0) red[w] = v;
    __syncthreads();
    if (threadIdx.x == 0) {
        float t = red[0] + red[1] + red[2] + red[3];
        atomicAdd(total_ws, t);
    }
}

// ---------- EMA embed_avg + normalize (runs last; overwrites eh/el scratch) ----------
__global__ void ema_embed_kernel(const float* __restrict__ embed_avg,
                                 const float* __restrict__ ncs, const float* __restrict__ total_ws,
                                 float* __restrict__ nea, float* __restrict__ enorm, int K)
{
    int gid = blockIdx.x * blockDim.x + threadIdx.x;
    if (gid >= K * D) return;
    int k = gid >> 6;
    float total = total_ws[0];
    float v = embed_avg[gid] * DECAYF + nea[gid] * OMDF;
    nea[gid] = v;
    float c = ncs[k];
    float smoothed = (c + EPSF) / (total + (float)K * EPSF) * total;
    enorm[gid] = v / smoothed;
}

extern "C" void kernel_launch(void* const* d_in, const int* in_sizes, int n_in,
                              void* d_out, int out_size, void* d_ws, size_t ws_size,
                              hipStream_t stream) {
    const float* x            = (const float*)d_in[0];   // [n, 64]
    const float* emb          = (const float*)d_in[1];   // [K, 64]
    const float* cluster_size = (const float*)d_in[2];   // [K]
    const float* embed_avg    = (const float*)d_in[3];   // [K, 64]

    const int n = in_sizes[0] / D;   // 16384
    const int K = in_sizes[1] / D;   // 8192

    // output layout (fp32): quantize | embed_ind | embed_normalized | new_cluster_size | new_embed_avg
    float* out     = (float*)d_out;
    float* quant   = out;                        // n*D
    float* out_ind = quant + (size_t)n * D;      // n
    float* enorm   = out_ind + n;                // K*D  (scratch for eh/el until final kernel)
    float* ncs     = enorm + (size_t)K * D;      // K
    float* nea     = ncs + K;                    // K*D

    f16* eh = reinterpret_cast<f16*>(enorm);     // K*D f16
    f16* el = eh + (size_t)K * D;                // K*D f16

    // workspace: e2 | pidx[NLIST][n] | idxf[n] | total
    float* e2    = (float*)d_ws;                       // K
    int*   pidx  = (int*)(e2 + K);                     // NLIST*n
    int*   idxf  = pidx + (size_t)NLIST * n;           // n
    float* total = (float*)(idxf + n);                 // 1

    hipMemsetAsync(ncs, 0, (size_t)K * sizeof(float), stream);
    hipMemsetAsync(nea, 0, (size_t)K * D * sizeof(float), stream);
    hipMemsetAsync(total, 0, sizeof(float), stream);

    prep_kernel<<<(K + 63) / 64, 64, 0, stream>>>(emb, eh, el, e2, K);
    argmin_kernel<<<(n / BM) * NCHUNK, 256, 0, stream>>>(x, eh, el, e2, pidx, n, K);
    rerank_kernel<<<(n + 255) / 256, 256, 0, stream>>>(x, emb, e2, pidx, out_ind, idxf, ncs, n);
    gather_scatter_kernel<<<((size_t)n * D + 255) / 256, 256, 0, stream>>>(x, emb, idxf, quant, nea, n);
    ema_cs_kernel<<<(K + 255) / 256, 256, 0, stream>>>(cluster_size, ncs, total, K);
    ema_embed_kernel<<<(K * D + 255) / 256, 256, 0, stream>>>(embed_avg, ncs, total, nea, enorm, K);
}